// Round 10
// baseline (463.628 us; speedup 1.0000x reference)
//
#include <hip/hip_runtime.h>
#include <hip/hip_bf16.h>
#include <math.h>

// ---------- types ----------
typedef short short8 __attribute__((ext_vector_type(8)));
typedef ushort ushort8v __attribute__((ext_vector_type(8)));
typedef float floatx4 __attribute__((ext_vector_type(4)));

__device__ __forceinline__ float bf2f(ushort u) {
    union { unsigned int i; float f; } v; v.i = ((unsigned int)u) << 16; return v.f;
}
__device__ __forceinline__ ushort f2bf(float f) {
    union { float f; unsigned int i; } v; v.f = f;
    unsigned int x = v.i;
    unsigned int lsb = (x >> 16) & 1u;
    x += 0x7fffu + lsb;
    return (ushort)(x >> 16);
}
__device__ __forceinline__ float gelu_f(float x) {
    return 0.5f * x * (1.0f + erff(x * 0.7071067811865475f));
}
__device__ __forceinline__ void store4(ushort* p, float a, float b, float c, float d) {
    ushort4 o; o.x = f2bf(a); o.y = f2bf(b); o.z = f2bf(c); o.w = f2bf(d);
    *(ushort4*)p = o;
}
__device__ __forceinline__ void store4(float* p, float a, float b, float c, float d) {
    *(float4*)p = make_float4(a, b, c, d);
}

// XCD-aware swizzle: flat id -> (x=N-tile, y=M-tile). bh = ny/8.
__device__ __forceinline__ int2 swz_xy(int id, int bh) {
    int xcd = id & 7;
    int s = id >> 3;
    int x = s / bh;
    int ry = s - x * bh;
    return make_int2(x, xcd * bh + ry);
}

// ---------- fused fp32 -> bf16 convert (weights + embeds): 8 segments ----------
struct CvtDesc {
    const float* in[8];
    ushort* out[8];
    int nblk[8];
};
__global__ __launch_bounds__(256) void cvt_all_kernel(CvtDesc d) {
    int b = blockIdx.x;
    int s = 0;
    int off = b;
    while (off >= d.nblk[s]) { off -= d.nblk[s]; s++; }
    int i = off * 1024 + threadIdx.x * 4;
    float4 v = *(const float4*)(d.in[s] + i);
    ushort4 o;
    o.x = f2bf(v.x); o.y = f2bf(v.y); o.z = f2bf(v.z); o.w = f2bf(v.w);
    *(ushort4*)(d.out[s] + i) = o;
}

// ---------- GEMM core v1 (128x128; qkv/gate1/proj) ----------
// Per-dispatch winner on the big-M GEMMs in every session (qkv: 118-121 us
// vs v2's 122-134). 4 blocks/CU -> inter-block wave overlap hides the
// per-K-step vmcnt drain; MfmaUtil ~40% = this structure's ceiling (m97).
template<int ACT, int AF32, typename TOUT>
__device__ __forceinline__ void gemm_core(const void* __restrict__ Av, int lda,
                                          const ushort* __restrict__ W,
                                          const float* __restrict__ bias,
                                          TOUT* __restrict__ C, int ldc,
                                          int K, int m0, int n0) {
    __shared__ ushort lsA[128 * 64];
    __shared__ ushort lsB[128 * 64];
    const int t = threadIdx.x;
    const int w = t >> 6, l = t & 63;
    const int q = l >> 4, r16 = l & 15;
    const int wm = (w >> 1) * 64, wn = (w & 1) * 64;

    floatx4 acc[4][4];
#pragma unroll
    for (int i = 0; i < 4; i++)
#pragma unroll
        for (int j = 0; j < 4; j++) acc[i][j] = (floatx4){0.f, 0.f, 0.f, 0.f};

    const int srow = t >> 3;
    const int lc   = t & 7;
    const int s7 = r16 & 7;
    const int e0 = ((q)     ^ s7) * 8;
    const int e1 = ((q + 4) ^ s7) * 8;

    for (int kt = 0; kt < K; kt += 64) {
        __syncthreads();
#pragma unroll
        for (int rr = 0; rr < 4; ++rr) {
            const int row = rr * 32 + srow;
            const int gc  = (lc ^ (row & 7)) * 8;
            const ushort* gb = W + (size_t)(n0 + row) * K + kt + gc;
            __builtin_amdgcn_global_load_lds((const __attribute__((address_space(1))) void*)gb,
                                             (__attribute__((address_space(3))) void*)&lsB[row * 64 + lc * 8],
                                             16, 0, 0);
            if (!AF32) {
                const ushort* ga = (const ushort*)Av + (size_t)(m0 + row) * lda + kt + gc;
                __builtin_amdgcn_global_load_lds((const __attribute__((address_space(1))) void*)ga,
                                                 (__attribute__((address_space(3))) void*)&lsA[row * 64 + lc * 8],
                                                 16, 0, 0);
            } else {
                const float* ga = (const float*)Av + (size_t)(m0 + row) * lda + kt + gc;
                float4 f0 = *(const float4*)ga;
                float4 f1 = *(const float4*)(ga + 4);
                ushort8v u;
                u[0] = f2bf(f0.x); u[1] = f2bf(f0.y); u[2] = f2bf(f0.z); u[3] = f2bf(f0.w);
                u[4] = f2bf(f1.x); u[5] = f2bf(f1.y); u[6] = f2bf(f1.z); u[7] = f2bf(f1.w);
                *(ushort8v*)&lsA[row * 64 + lc * 8] = u;
            }
        }
        __syncthreads();
        {
            short8 af[4], bfr[4];
#pragma unroll
            for (int i = 0; i < 4; i++) af[i]  = *(const short8*)&lsA[(wm + i * 16 + r16) * 64 + e0];
#pragma unroll
            for (int j = 0; j < 4; j++) bfr[j] = *(const short8*)&lsB[(wn + j * 16 + r16) * 64 + e0];
#pragma unroll
            for (int i = 0; i < 4; i++)
#pragma unroll
                for (int j = 0; j < 4; j++)
                    acc[i][j] = __builtin_amdgcn_mfma_f32_16x16x32_bf16(bfr[j], af[i], acc[i][j], 0, 0, 0);
#pragma unroll
            for (int i = 0; i < 4; i++) af[i]  = *(const short8*)&lsA[(wm + i * 16 + r16) * 64 + e1];
#pragma unroll
            for (int j = 0; j < 4; j++) bfr[j] = *(const short8*)&lsB[(wn + j * 16 + r16) * 64 + e1];
#pragma unroll
            for (int i = 0; i < 4; i++)
#pragma unroll
                for (int j = 0; j < 4; j++)
                    acc[i][j] = __builtin_amdgcn_mfma_f32_16x16x32_bf16(bfr[j], af[i], acc[i][j], 0, 0, 0);
        }
    }

    // epilogue: i outer / j inner (line-completing store order); bias hoisted
    {
        float4 bv[4];
#pragma unroll
        for (int j = 0; j < 4; j++) bv[j] = *(const float4*)(bias + n0 + wn + j * 16 + q * 4);
#pragma unroll
        for (int i = 0; i < 4; i++) {
            const int row = m0 + wm + i * 16 + r16;
#pragma unroll
            for (int j = 0; j < 4; j++) {
                const int col = n0 + wn + j * 16 + q * 4;
                float v0 = acc[i][j][0] + bv[j].x;
                float v1 = acc[i][j][1] + bv[j].y;
                float v2 = acc[i][j][2] + bv[j].z;
                float v3 = acc[i][j][3] + bv[j].w;
                if (ACT == 1) { v0 = gelu_f(v0); v1 = gelu_f(v1); v2 = gelu_f(v2); v3 = gelu_f(v3); }
                store4(&C[(size_t)row * ldc + col], v0, v1, v2, v3);
            }
        }
    }
}

template<int ACT, typename TOUT>
__global__ __launch_bounds__(256, 4) void gemm_bt(const ushort* __restrict__ A, int lda,
                                                  const ushort* __restrict__ W,
                                                  const float* __restrict__ bias,
                                                  TOUT* __restrict__ C, int ldc, int K,
                                                  int bh) {
    int2 xy = swz_xy(blockIdx.x, bh);
    gemm_core<ACT, 0, TOUT>(A, lda, W, bias, C, ldc, K, xy.y * 128, xy.x * 128);
}

// ---------- GEMM core v2: 256x256 8-phase DEEP de-pinned (embed/attn_out) ----------
// R8-verified best v2 variant (bare s_waitcnt, no sched_barrier pins; deep
// slot map with 3-4 phase fence lead). ~35% MfmaUtil = this structure's
// plain-HIP plateau in our hands; kept where it beats v1 (embed, attn_out).
#define G8_BAR() __builtin_amdgcn_s_barrier()
#define G8_LGKM0() asm volatile("s_waitcnt lgkmcnt(0)" ::: "memory")
#define G8_VM(N) asm volatile("s_waitcnt vmcnt(" #N ")" ::: "memory")
#define G8_GLDS(gp, lp) __builtin_amdgcn_global_load_lds( \
    (const __attribute__((address_space(1))) void*)(gp), \
    (__attribute__((address_space(3))) void*)(lp), 16, 0, 0)

#define G8_QUAD(I0, J0) do { \
    __builtin_amdgcn_s_setprio(1); \
    _Pragma("unroll") \
    for (int ii = 0; ii < 4; ++ii) \
    _Pragma("unroll") \
    for (int jj = 0; jj < 2; ++jj) \
    _Pragma("unroll") \
    for (int ss = 0; ss < 2; ++ss) \
        acc[(I0)+ii][(J0)+jj] = __builtin_amdgcn_mfma_f32_16x16x32_bf16( \
            Bf[(J0)+jj][ss], Af[ii][ss], acc[(I0)+ii][(J0)+jj], 0, 0, 0); \
    __builtin_amdgcn_s_setprio(0); } while (0)

#define G8_RDA(buf, i0) do { _Pragma("unroll") \
    for (int ii = 0; ii < 4; ++ii) { \
        Af[ii][0] = rdA(buf, (i0)+ii, 0); \
        Af[ii][1] = rdA(buf, (i0)+ii, 1); } } while (0)
#define G8_RDB(buf, j0) do { _Pragma("unroll") \
    for (int jj = 0; jj < 2; ++jj) { \
        Bf[(j0)+jj][0] = rdB(buf, (j0)+jj, 0); \
        Bf[(j0)+jj][1] = rdB(buf, (j0)+jj, 1); } } while (0)

template<int ACT, int LDA, int KK, typename TOUT>
__device__ __forceinline__ void gemm8_core(const ushort* __restrict__ A,
                                           const ushort* __restrict__ W,
                                           const float* __restrict__ bias,
                                           TOUT* __restrict__ C, int ldc,
                                           int m0, int n0) {
    __shared__ ushort ls[4][16384];   // [buf*2 + mat][256*64]; 128 KiB
    const int t = threadIdx.x;
    const int w = t >> 6, l = t & 63;
    const int q = l >> 4, r16 = l & 15;
    const int s7 = r16 & 7;
    const int wm = (w >> 2) * 128;    // wave row band (2 M-waves)
    const int wn = (w & 3) * 64;      // wave col band (4 N-waves)
    const int srow = t >> 3;          // 0..63
    const int lc = t & 7;

    const int gc = (lc ^ (srow & 7)) * 8;
    const ushort* baseA = A + (size_t)(m0 + srow) * LDA + gc;
    const ushort* baseW = W + (size_t)(n0 + srow) * KK + gc;
    const int aoff = (wm + r16) * 64;
    const int boff = (wn + r16) * 64;
    const int e0 = (q ^ s7) * 8;
    const int e1 = e0 ^ 32;

    floatx4 acc[8][4];
#pragma unroll
    for (int i = 0; i < 8; ++i)
#pragma unroll
        for (int j = 0; j < 4; ++j) acc[i][j] = (floatx4){0.f, 0.f, 0.f, 0.f};

    short8 Af[4][2], Bf[4][2];

    auto stage = [&](int buf, int mat, int half, int kt) {
        const ushort* bp = mat ? baseW : baseA;
#pragma unroll
        for (int L = 0; L < 2; ++L) {
            const ushort* gp = bp + (size_t)(half * 128 + L * 64) * (mat ? KK : LDA) + kt;
            ushort* lp = &ls[buf * 2 + mat][half * 8192 + L * 4096 + t * 8];
            G8_GLDS(gp, lp);
        }
    };
    auto rdA = [&](int buf, int i, int s) -> short8 {
        return *(const short8*)&ls[buf * 2][aoff + i * 1024 + (s ? e1 : e0)];
    };
    auto rdB = [&](int buf, int j, int s) -> short8 {
        return *(const short8*)&ls[buf * 2 + 1][boff + j * 1024 + (s ? e1 : e0)];
    };

    const int NT = KK >> 6;   // even

    // prologue: buf0 full (8) + buf1-B (4) + buf1-A-h0 (2); VM(6) -> buf0 done
    stage(0, 0, 0, 0);  stage(0, 0, 1, 0);  stage(0, 1, 0, 0);  stage(0, 1, 1, 0);
    stage(1, 1, 0, 64); stage(1, 1, 1, 64); stage(1, 0, 0, 64);
    G8_VM(6);
    G8_BAR();

    for (int tt = 0; tt < NT; tt += 2) {
        const bool pf = (tt + 2) < NT;
        const int kO  = (tt + 1) << 6;
        const int kE2 = (tt + 2) << 6;
        const int kO2 = (tt + 3) << 6;

        // ---- p1: q1(even); stage buf1-A-h1 @ kO ----
        G8_RDA(0, 0); G8_RDB(0, 0);
        stage(1, 0, 1, kO);
        G8_BAR(); G8_LGKM0();
        G8_QUAD(0, 0);
        G8_BAR();
        // ---- p2: q2(even); no stage ----
        G8_RDB(0, 2);
        G8_BAR(); G8_LGKM0();
        G8_QUAD(0, 2);
        G8_BAR();
        // ---- p3: q3(even); stage buf0-B-h0 @ kE2 ----
        G8_RDA(0, 4);
        if (pf) stage(0, 1, 0, kE2);
        G8_BAR(); G8_LGKM0();
        G8_QUAD(4, 0);
        G8_BAR();
        // ---- p4: q4(even); stage buf0-B-h1 + buf0-A-h0 @ kE2; fence buf1@kO ----
        if (pf) { stage(0, 1, 1, kE2); stage(0, 0, 0, kE2); }
        G8_BAR();
        G8_QUAD(4, 2);
        if (pf) G8_VM(6); else G8_VM(0);
        G8_BAR();
        // ---- p5: q1(odd); stage buf0-A-h1 @ kE2 ----
        G8_RDA(1, 0); G8_RDB(1, 0);
        if (pf) stage(0, 0, 1, kE2);
        G8_BAR(); G8_LGKM0();
        G8_QUAD(0, 0);
        G8_BAR();
        // ---- p6: q2(odd); no stage ----
        G8_RDB(1, 2);
        G8_BAR(); G8_LGKM0();
        G8_QUAD(0, 2);
        G8_BAR();
        // ---- p7: q3(odd); stage buf1-B-h0 @ kO2 ----
        G8_RDA(1, 4);
        if (pf) stage(1, 1, 0, kO2);
        G8_BAR(); G8_LGKM0();
        G8_QUAD(4, 0);
        G8_BAR();
        // ---- p8: q4(odd); stage buf1-B-h1 + buf1-A-h0 @ kO2; fence buf0@kE2 ----
        if (pf) { stage(1, 1, 1, kO2); stage(1, 0, 0, kO2); }
        G8_BAR();
        G8_QUAD(4, 2);
        if (pf) G8_VM(6);
        G8_BAR();
    }

    // epilogue: i outer / j inner (line-completing store order)
#pragma unroll
    for (int i = 0; i < 8; ++i) {
        const int row = m0 + wm + i * 16 + r16;
#pragma unroll
        for (int j = 0; j < 4; ++j) {
            const int col = n0 + wn + j * 16 + q * 4;
            const float4 bv = *(const float4*)(bias + col);
            float v0 = acc[i][j][0] + bv.x;
            float v1 = acc[i][j][1] + bv.y;
            float v2 = acc[i][j][2] + bv.z;
            float v3 = acc[i][j][3] + bv.w;
            if (ACT == 1) { v0 = gelu_f(v0); v1 = gelu_f(v1); v2 = gelu_f(v2); v3 = gelu_f(v3); }
            store4(&C[(size_t)row * ldc + col], v0, v1, v2, v3);
        }
    }
}

template<int ACT, int LDA, int KK, typename TOUT>
__global__ __launch_bounds__(512, 2) void gemm8_bt(const ushort* __restrict__ A,
                                                   const ushort* __restrict__ W,
                                                   const float* __restrict__ bias,
                                                   TOUT* __restrict__ C, int ldc,
                                                   int bh) {
    int2 xy = swz_xy(blockIdx.x, bh);
    gemm8_core<ACT, LDA, KK, TOUT>(A, W, bias, C, ldc, xy.y * 256, xy.x * 256);
}

// both embed GEMMs in one dispatch; A pre-converted to bf16 by cvt_all
__global__ __launch_bounds__(512, 2) void embed8_gemm(const ushort* __restrict__ A0,
                                                      const ushort* __restrict__ A1,
                                                      const ushort* __restrict__ W0,
                                                      const ushort* __restrict__ W1,
                                                      const float* __restrict__ b0,
                                                      const float* __restrict__ b1,
                                                      ushort* __restrict__ C) {
    const int z = blockIdx.z;
    int2 xy = swz_xy(blockIdx.x, 4);   // ny=32 -> bh=4
    gemm8_core<0, 512, 512, ushort>(z ? A1 : A0, z ? W1 : W0, z ? b1 : b0,
                                    C + z * 1024, 2048, xy.y * 256, xy.x * 256);
}

// ---------- LayerNorm in place over rows of combined (16384 x 1024 bf16) ----------
__global__ __launch_bounds__(256) void ln_kernel(ushort* __restrict__ comb,
                                                 const float* __restrict__ g1, const float* __restrict__ b1,
                                                 const float* __restrict__ g2, const float* __restrict__ b2) {
    int row = blockIdx.x;
    int s = row & 1;
    const float* g = s ? g2 : g1;
    const float* bb = s ? b2 : b1;
    ushort* p = comb + (size_t)row * 1024;
    int t = threadIdx.x;
    ushort4 u = *(const ushort4*)(p + t * 4);
    float x0 = bf2f(u.x), x1 = bf2f(u.y), x2 = bf2f(u.z), x3 = bf2f(u.w);
    float sum = x0 + x1 + x2 + x3;
    float ss = x0 * x0 + x1 * x1 + x2 * x2 + x3 * x3;
#pragma unroll
    for (int off = 32; off; off >>= 1) {
        sum += __shfl_xor(sum, off);
        ss  += __shfl_xor(ss, off);
    }
    __shared__ float sm[8];
    int wv = t >> 6, l = t & 63;
    if (l == 0) { sm[wv * 2] = sum; sm[wv * 2 + 1] = ss; }
    __syncthreads();
    sum = sm[0] + sm[2] + sm[4] + sm[6];
    ss  = sm[1] + sm[3] + sm[5] + sm[7];
    float mean = sum * (1.0f / 1024.0f);
    float var  = ss * (1.0f / 1024.0f) - mean * mean;
    float rstd = rsqrtf(var + 1e-5f);
    float4 gv = *(const float4*)(g + t * 4);
    float4 bv = *(const float4*)(bb + t * 4);
    ushort4 o;
    o.x = f2bf((x0 - mean) * rstd * gv.x + bv.x);
    o.y = f2bf((x1 - mean) * rstd * gv.y + bv.y);
    o.z = f2bf((x2 - mean) * rstd * gv.z + bv.z);
    o.w = f2bf((x3 - mean) * rstd * gv.w + bv.w);
    *(ushort4*)(p + t * 4) = o;
}

// ---------- attention v3 (R10): direct loads, no LDS staging ----------
// R9 audit: the old LDS stage was an identity mapping — consumption index
// o0 = (t>>5)*128 + (t&31)*4 == 4*t, so every thread read LDS at exactly
// its own linear offset. Common-mistake #7: staging that redistributes
// nothing is pure overhead. Direct ushort4 global loads at src+4t (+k*1024)
// are perfectly coalesced (8 B/lane); drops 3 LDS writes + 6 LDS reads +
// 1 barrier per block. Shuffle reduce (off<=16, within 32-lane head group)
// unchanged.
__global__ __launch_bounds__(256) void attn_kernel(const ushort* __restrict__ qkv,
                                                   ushort* __restrict__ O) {
    const int b = blockIdx.x;
    const int t = threadIdx.x;
    const ushort* src = qkv + (size_t)b * 6144;
    const int o0 = t * 4;
    ushort4 uq0 = *(const ushort4*)&src[o0];
    ushort4 uk0 = *(const ushort4*)&src[1024 + o0];
    ushort4 uv0 = *(const ushort4*)&src[2048 + o0];
    ushort4 uq1 = *(const ushort4*)&src[3072 + o0];
    ushort4 uk1 = *(const ushort4*)&src[4096 + o0];
    ushort4 uv1 = *(const ushort4*)&src[5120 + o0];
    float q0[4] = {bf2f(uq0.x), bf2f(uq0.y), bf2f(uq0.z), bf2f(uq0.w)};
    float q1[4] = {bf2f(uq1.x), bf2f(uq1.y), bf2f(uq1.z), bf2f(uq1.w)};
    float k0[4] = {bf2f(uk0.x), bf2f(uk0.y), bf2f(uk0.z), bf2f(uk0.w)};
    float k1[4] = {bf2f(uk1.x), bf2f(uk1.y), bf2f(uk1.z), bf2f(uk1.w)};
    float v0[4] = {bf2f(uv0.x), bf2f(uv0.y), bf2f(uv0.z), bf2f(uv0.w)};
    float v1[4] = {bf2f(uv1.x), bf2f(uv1.y), bf2f(uv1.z), bf2f(uv1.w)};
    float p00 = 0.f, p01 = 0.f, p10 = 0.f, p11 = 0.f;
#pragma unroll
    for (int i = 0; i < 4; i++) {
        p00 += q0[i] * k0[i];
        p01 += q0[i] * k1[i];
        p10 += q1[i] * k0[i];
        p11 += q1[i] * k1[i];
    }
#pragma unroll
    for (int off = 16; off; off >>= 1) {
        p00 += __shfl_xor(p00, off);
        p01 += __shfl_xor(p01, off);
        p10 += __shfl_xor(p10, off);
        p11 += __shfl_xor(p11, off);
    }
    const float sc = 0.08838834764831845f;  // 1/sqrt(128)
    p00 *= sc; p01 *= sc; p10 *= sc; p11 *= sc;
    float m0 = fmaxf(p00, p01), m1 = fmaxf(p10, p11);
    float e00 = expf(p00 - m0), e01 = expf(p01 - m0);
    float e10 = expf(p10 - m1), e11 = expf(p11 - m1);
    float i0 = 1.0f / (e00 + e01), i1 = 1.0f / (e10 + e11);
    float a00 = e00 * i0, a01 = e01 * i0;
    float a10 = e10 * i1, a11 = e11 * i1;
    ushort* dst0 = O + (size_t)(b * 2) * 1024 + o0;
    ushort* dst1 = dst0 + 1024;
    store4(dst0, a00 * v0[0] + a01 * v1[0], a00 * v0[1] + a01 * v1[1],
                 a00 * v0[2] + a01 * v1[2], a00 * v0[3] + a01 * v1[3]);
    store4(dst1, a10 * v0[0] + a11 * v1[0], a10 * v0[1] + a11 * v1[1],
                 a10 * v0[2] + a11 * v1[2], a10 * v0[3] + a11 * v1[3]);
}

// ---------- gate2 (dot over 1024 x2) + softmax + fused combine ----------
__global__ __launch_bounds__(256) void gate2_kernel(const ushort* __restrict__ gate_h,
                                                    const float* __restrict__ w2, const float* __restrict__ b2,
                                                    const ushort* __restrict__ attn_out,
                                                    ushort* __restrict__ fused_pre,
                                                    float* __restrict__ gw_out) {
    int b = blockIdx.x;
    int t = threadIdx.x;
    const ushort* hp = gate_h + (size_t)b * 1024;
    ushort4 u = *(const ushort4*)(hp + t * 4);
    float4 w0 = *(const float4*)(w2 + t * 4);
    float4 w1 = *(const float4*)(w2 + 1024 + t * 4);
    float h0 = bf2f(u.x), h1 = bf2f(u.y), h2 = bf2f(u.z), h3 = bf2f(u.w);
    float p0 = h0 * w0.x + h1 * w0.y + h2 * w0.z + h3 * w0.w;
    float p1 = h0 * w1.x + h1 * w1.y + h2 * w1.z + h3 * w1.w;
#pragma unroll
    for (int off = 32; off; off >>= 1) {
        p0 += __shfl_xor(p0, off);
        p1 += __shfl_xor(p1, off);
    }
    __shared__ float sm[8];
    __shared__ float sgw[2];
    int wv = t >> 6, l = t & 63;
    if (l == 0) { sm[wv * 2] = p0; sm[wv * 2 + 1] = p1; }
    __syncthreads();
    if (t == 0) {
        float d0 = sm[0] + sm[2] + sm[4] + sm[6] + b2[0];
        float d1 = sm[1] + sm[3] + sm[5] + sm[7] + b2[1];
        float mx = fmaxf(d0, d1);
        float e0 = expf(d0 - mx), e1 = expf(d1 - mx);
        float inv = 1.0f / (e0 + e1);
        sgw[0] = e0 * inv; sgw[1] = e1 * inv;
        gw_out[b * 2] = e0 * inv;
        gw_out[b * 2 + 1] = e1 * inv;
    }
    __syncthreads();
    float g0 = sgw[0], g1 = sgw[1];
    const ushort* ca = attn_out + (size_t)b * 2048;
    ushort* fp = fused_pre + (size_t)b * 1024;
    ushort4 uc = *(const ushort4*)(ca + t * 4);
    ushort4 ug = *(const ushort4*)(ca + 1024 + t * 4);
    ushort4 o;
    o.x = f2bf(g0 * bf2f(uc.x) + g1 * bf2f(ug.x));
    o.y = f2bf(g0 * bf2f(uc.y) + g1 * bf2f(ug.y));
    o.z = f2bf(g0 * bf2f(uc.z) + g1 * bf2f(ug.z));
    o.w = f2bf(g0 * bf2f(uc.w) + g1 * bf2f(ug.w));
    *(ushort4*)(fp + t * 4) = o;
}

// ---------- workspace layout (bytes) ----------
// [0, 16M): bf16 embeds (e_cnn 8 MB, e_gnn 8 MB)
// OFF_COMB region is time-multiplexed: comb -> O -> gate_h / fused_pre
#define OFF_E_CNN  0u
#define OFF_E_GNN  8388608u
#define OFF_W_CNN  16777216u
#define OFF_W_GNN  17825792u
#define OFF_W_QKV  18874368u
#define OFF_W_AO   25165824u
#define OFF_W_G1   27262976u
#define OFF_W_PJ   31457280u
#define OFF_COMB   33554432u
#define OFF_QKV    67108864u   /* 16384x3072 bf16 */
#define OFF_AO     167772160u  /* 16384x1024 bf16 == gate_in (8192 x 2048) */

extern "C" void kernel_launch(void* const* d_in, const int* in_sizes, int n_in,
                              void* d_out, int out_size, void* d_ws, size_t ws_size,
                              hipStream_t stream) {
    const float* cnn_embed  = (const float*)d_in[0];
    const float* gnn_embed  = (const float*)d_in[1];
    const float* cnn_w      = (const float*)d_in[2];
    const float* cnn_b      = (const float*)d_in[3];
    const float* gnn_w      = (const float*)d_in[4];
    const float* gnn_b      = (const float*)d_in[5];
    const float* ln1_g      = (const float*)d_in[6];
    const float* ln1_b      = (const float*)d_in[7];
    const float* ln2_g      = (const float*)d_in[8];
    const float* ln2_b      = (const float*)d_in[9];
    const float* attn_in_w  = (const float*)d_in[10];
    const float* attn_in_b  = (const float*)d_in[11];
    const float* attn_out_w = (const float*)d_in[12];
    const float* attn_out_b = (const float*)d_in[13];
    const float* gate_w1    = (const float*)d_in[14];
    const float* gate_b1    = (const float*)d_in[15];
    const float* gate_w2    = (const float*)d_in[16];
    const float* gate_b2    = (const float*)d_in[17];
    const float* proj_w     = (const float*)d_in[18];
    const float* proj_b     = (const float*)d_in[19];

    char* ws = (char*)d_ws;
    ushort* e_cnn  = (ushort*)(ws + OFF_E_CNN);
    ushort* e_gnn  = (ushort*)(ws + OFF_E_GNN);
    ushort* w_cnn  = (ushort*)(ws + OFF_W_CNN);
    ushort* w_gnn  = (ushort*)(ws + OFF_W_GNN);
    ushort* w_qkv  = (ushort*)(ws + OFF_W_QKV);
    ushort* w_ao   = (ushort*)(ws + OFF_W_AO);
    ushort* w_g1   = (ushort*)(ws + OFF_W_G1);
    ushort* w_pj   = (ushort*)(ws + OFF_W_PJ);
    ushort* comb   = (ushort*)(ws + OFF_COMB);
    ushort* qkv    = (ushort*)(ws + OFF_QKV);
    ushort* ao     = (ushort*)(ws + OFF_AO);
    ushort* Obuf      = (ushort*)(ws + OFF_COMB);              // alias: comb dead after qkv GEMM
    ushort* gate_h    = (ushort*)(ws + OFF_COMB);              // alias: O dead after attn_out GEMM
    ushort* fused_pre = (ushort*)(ws + OFF_COMB + 16777216u);

    float* out_f  = (float*)d_out;
    float* gw_out = out_f + 8192 * 1024;

    // ---- fp32 -> bf16 converts (weights + both embeds) in one dispatch ----
    CvtDesc cd;
    cd.in[0] = cnn_w;      cd.out[0] = w_cnn; cd.nblk[0] = 512;
    cd.in[1] = gnn_w;      cd.out[1] = w_gnn; cd.nblk[1] = 512;
    cd.in[2] = attn_in_w;  cd.out[2] = w_qkv; cd.nblk[2] = 3072;
    cd.in[3] = attn_out_w; cd.out[3] = w_ao;  cd.nblk[3] = 1024;
    cd.in[4] = gate_w1;    cd.out[4] = w_g1;  cd.nblk[4] = 2048;
    cd.in[5] = proj_w;     cd.out[5] = w_pj;  cd.nblk[5] = 1024;
    cd.in[6] = cnn_embed;  cd.out[6] = e_cnn; cd.nblk[6] = 4096;
    cd.in[7] = gnn_embed;  cd.out[7] = e_gnn; cd.nblk[7] = 4096;
    cvt_all_kernel<<<16384, 256, 0, stream>>>(cd);

    dim3 blk256(256);
    dim3 blk512(512);

    // ---- both embed GEMMs (8-phase DEEP depinned; nx=4, ny=32, bh=4) ----
    embed8_gemm<<<dim3(128, 1, 2), blk512, 0, stream>>>(e_cnn, e_gnn, w_cnn, w_gnn,
                                                        cnn_b, gnn_b, comb);

    // ---- LayerNorm in place ----
    ln_kernel<<<16384, blk256, 0, stream>>>(comb, ln1_g, ln1_b, ln2_g, ln2_b);

    // ---- qkv GEMM: v1 128^2 (per-dispatch winner; nx=24, ny=128, bh=16) ----
    gemm_bt<0, ushort><<<24 * 128, blk256, 0, stream>>>(comb, 1024, w_qkv, attn_in_b,
                                                        qkv, 3072, 1024, 16);

    // ---- attention -> compact O (direct-load v3) ----
    attn_kernel<<<8192, blk256, 0, stream>>>(qkv, Obuf);

    // ---- attn_out GEMM (8-phase DEEP depinned 256^2; nx=4, ny=64, bh=8) ----
    gemm8_bt<0, 1024, 1024, ushort><<<4 * 64, blk512, 0, stream>>>(Obuf, w_ao, attn_out_b,
                                                                   ao, 1024, 8);

    // ---- gate1 GEMM (gelu) (v1 128^2: nx=8, ny=64, bh=8 -> 512 blocks) ----
    gemm_bt<1, ushort><<<8 * 64, blk256, 0, stream>>>(ao, 2048, w_g1, gate_b1, gate_h, 1024, 2048, 8);

    // ---- gate2 + softmax + fused combine ----
    gate2_kernel<<<8192, blk256, 0, stream>>>(gate_h, gate_w2, gate_b2, ao, fused_pre, gw_out);

    // ---- proj GEMM (gelu) -> out (v1 128^2: nx=8, ny=64, bh=8) ----
    gemm_bt<1, float><<<8 * 64, blk256, 0, stream>>>(fused_pre, 1024, w_pj, proj_b, out_f, 1024, 1024, 8);
}

// Round 11
// 433.200 us; speedup vs baseline: 1.0702x; 1.0702x over previous
//
#include <hip/hip_runtime.h>
#include <hip/hip_bf16.h>
#include <math.h>

// ---------- types ----------
typedef short short8 __attribute__((ext_vector_type(8)));
typedef ushort ushort8v __attribute__((ext_vector_type(8)));
typedef float floatx4 __attribute__((ext_vector_type(4)));

__device__ __forceinline__ float bf2f(ushort u) {
    union { unsigned int i; float f; } v; v.i = ((unsigned int)u) << 16; return v.f;
}
__device__ __forceinline__ ushort f2bf(float f) {
    union { float f; unsigned int i; } v; v.f = f;
    unsigned int x = v.i;
    unsigned int lsb = (x >> 16) & 1u;
    x += 0x7fffu + lsb;
    return (ushort)(x >> 16);
}
__device__ __forceinline__ float gelu_f(float x) {
    return 0.5f * x * (1.0f + erff(x * 0.7071067811865475f));
}
__device__ __forceinline__ void store4(ushort* p, float a, float b, float c, float d) {
    ushort4 o; o.x = f2bf(a); o.y = f2bf(b); o.z = f2bf(c); o.w = f2bf(d);
    *(ushort4*)p = o;
}
__device__ __forceinline__ void store4(float* p, float a, float b, float c, float d) {
    *(float4*)p = make_float4(a, b, c, d);
}

// XCD-aware swizzle: flat id -> (x=N-tile, y=M-tile). bh = ny/8.
__device__ __forceinline__ int2 swz_xy(int id, int bh) {
    int xcd = id & 7;
    int s = id >> 3;
    int x = s / bh;
    int ry = s - x * bh;
    return make_int2(x, xcd * bh + ry);
}

// ---------- fused fp32 -> bf16 convert (weights + embeds): 8 segments ----------
struct CvtDesc {
    const float* in[8];
    ushort* out[8];
    int nblk[8];
};
__global__ __launch_bounds__(256) void cvt_all_kernel(CvtDesc d) {
    int b = blockIdx.x;
    int s = 0;
    int off = b;
    while (off >= d.nblk[s]) { off -= d.nblk[s]; s++; }
    int i = off * 1024 + threadIdx.x * 4;
    float4 v = *(const float4*)(d.in[s] + i);
    ushort4 o;
    o.x = f2bf(v.x); o.y = f2bf(v.y); o.z = f2bf(v.z); o.w = f2bf(v.w);
    *(ushort4*)(d.out[s] + i) = o;
}

// ---------- GEMM core v1 (128x128; qkv/gate1/proj) ----------
// Per-dispatch winner on the big-M GEMMs in every session (qkv: 118-121 us
// vs v2's 122-134). 4 blocks/CU -> inter-block wave overlap hides the
// per-K-step vmcnt drain; MfmaUtil ~40% = this structure's ceiling (m97).
template<int ACT, int AF32, typename TOUT>
__device__ __forceinline__ void gemm_core(const void* __restrict__ Av, int lda,
                                          const ushort* __restrict__ W,
                                          const float* __restrict__ bias,
                                          TOUT* __restrict__ C, int ldc,
                                          int K, int m0, int n0) {
    __shared__ ushort lsA[128 * 64];
    __shared__ ushort lsB[128 * 64];
    const int t = threadIdx.x;
    const int w = t >> 6, l = t & 63;
    const int q = l >> 4, r16 = l & 15;
    const int wm = (w >> 1) * 64, wn = (w & 1) * 64;

    floatx4 acc[4][4];
#pragma unroll
    for (int i = 0; i < 4; i++)
#pragma unroll
        for (int j = 0; j < 4; j++) acc[i][j] = (floatx4){0.f, 0.f, 0.f, 0.f};

    const int srow = t >> 3;
    const int lc   = t & 7;
    const int s7 = r16 & 7;
    const int e0 = ((q)     ^ s7) * 8;
    const int e1 = ((q + 4) ^ s7) * 8;

    for (int kt = 0; kt < K; kt += 64) {
        __syncthreads();
#pragma unroll
        for (int rr = 0; rr < 4; ++rr) {
            const int row = rr * 32 + srow;
            const int gc  = (lc ^ (row & 7)) * 8;
            const ushort* gb = W + (size_t)(n0 + row) * K + kt + gc;
            __builtin_amdgcn_global_load_lds((const __attribute__((address_space(1))) void*)gb,
                                             (__attribute__((address_space(3))) void*)&lsB[row * 64 + lc * 8],
                                             16, 0, 0);
            if (!AF32) {
                const ushort* ga = (const ushort*)Av + (size_t)(m0 + row) * lda + kt + gc;
                __builtin_amdgcn_global_load_lds((const __attribute__((address_space(1))) void*)ga,
                                                 (__attribute__((address_space(3))) void*)&lsA[row * 64 + lc * 8],
                                                 16, 0, 0);
            } else {
                const float* ga = (const float*)Av + (size_t)(m0 + row) * lda + kt + gc;
                float4 f0 = *(const float4*)ga;
                float4 f1 = *(const float4*)(ga + 4);
                ushort8v u;
                u[0] = f2bf(f0.x); u[1] = f2bf(f0.y); u[2] = f2bf(f0.z); u[3] = f2bf(f0.w);
                u[4] = f2bf(f1.x); u[5] = f2bf(f1.y); u[6] = f2bf(f1.z); u[7] = f2bf(f1.w);
                *(ushort8v*)&lsA[row * 64 + lc * 8] = u;
            }
        }
        __syncthreads();
        {
            short8 af[4], bfr[4];
#pragma unroll
            for (int i = 0; i < 4; i++) af[i]  = *(const short8*)&lsA[(wm + i * 16 + r16) * 64 + e0];
#pragma unroll
            for (int j = 0; j < 4; j++) bfr[j] = *(const short8*)&lsB[(wn + j * 16 + r16) * 64 + e0];
#pragma unroll
            for (int i = 0; i < 4; i++)
#pragma unroll
                for (int j = 0; j < 4; j++)
                    acc[i][j] = __builtin_amdgcn_mfma_f32_16x16x32_bf16(bfr[j], af[i], acc[i][j], 0, 0, 0);
#pragma unroll
            for (int i = 0; i < 4; i++) af[i]  = *(const short8*)&lsA[(wm + i * 16 + r16) * 64 + e1];
#pragma unroll
            for (int j = 0; j < 4; j++) bfr[j] = *(const short8*)&lsB[(wn + j * 16 + r16) * 64 + e1];
#pragma unroll
            for (int i = 0; i < 4; i++)
#pragma unroll
                for (int j = 0; j < 4; j++)
                    acc[i][j] = __builtin_amdgcn_mfma_f32_16x16x32_bf16(bfr[j], af[i], acc[i][j], 0, 0, 0);
        }
    }

    // epilogue: i outer / j inner (line-completing store order); bias hoisted
    {
        float4 bv[4];
#pragma unroll
        for (int j = 0; j < 4; j++) bv[j] = *(const float4*)(bias + n0 + wn + j * 16 + q * 4);
#pragma unroll
        for (int i = 0; i < 4; i++) {
            const int row = m0 + wm + i * 16 + r16;
#pragma unroll
            for (int j = 0; j < 4; j++) {
                const int col = n0 + wn + j * 16 + q * 4;
                float v0 = acc[i][j][0] + bv[j].x;
                float v1 = acc[i][j][1] + bv[j].y;
                float v2 = acc[i][j][2] + bv[j].z;
                float v3 = acc[i][j][3] + bv[j].w;
                if (ACT == 1) { v0 = gelu_f(v0); v1 = gelu_f(v1); v2 = gelu_f(v2); v3 = gelu_f(v3); }
                store4(&C[(size_t)row * ldc + col], v0, v1, v2, v3);
            }
        }
    }
}

template<int ACT, typename TOUT>
__global__ __launch_bounds__(256, 4) void gemm_bt(const ushort* __restrict__ A, int lda,
                                                  const ushort* __restrict__ W,
                                                  const float* __restrict__ bias,
                                                  TOUT* __restrict__ C, int ldc, int K,
                                                  int bh) {
    int2 xy = swz_xy(blockIdx.x, bh);
    gemm_core<ACT, 0, TOUT>(A, lda, W, bias, C, ldc, K, xy.y * 128, xy.x * 128);
}

// ---------- GEMM core v2: 256x256 8-phase DEEP de-pinned (embed/attn_out) ----------
// R8-verified best v2 variant (bare s_waitcnt, no sched_barrier pins; deep
// slot map with 3-4 phase fence lead). ~35% MfmaUtil = this structure's
// plain-HIP plateau in our hands; kept where it beats v1 (embed, attn_out).
#define G8_BAR() __builtin_amdgcn_s_barrier()
#define G8_LGKM0() asm volatile("s_waitcnt lgkmcnt(0)" ::: "memory")
#define G8_VM(N) asm volatile("s_waitcnt vmcnt(" #N ")" ::: "memory")
#define G8_GLDS(gp, lp) __builtin_amdgcn_global_load_lds( \
    (const __attribute__((address_space(1))) void*)(gp), \
    (__attribute__((address_space(3))) void*)(lp), 16, 0, 0)

#define G8_QUAD(I0, J0) do { \
    __builtin_amdgcn_s_setprio(1); \
    _Pragma("unroll") \
    for (int ii = 0; ii < 4; ++ii) \
    _Pragma("unroll") \
    for (int jj = 0; jj < 2; ++jj) \
    _Pragma("unroll") \
    for (int ss = 0; ss < 2; ++ss) \
        acc[(I0)+ii][(J0)+jj] = __builtin_amdgcn_mfma_f32_16x16x32_bf16( \
            Bf[(J0)+jj][ss], Af[ii][ss], acc[(I0)+ii][(J0)+jj], 0, 0, 0); \
    __builtin_amdgcn_s_setprio(0); } while (0)

#define G8_RDA(buf, i0) do { _Pragma("unroll") \
    for (int ii = 0; ii < 4; ++ii) { \
        Af[ii][0] = rdA(buf, (i0)+ii, 0); \
        Af[ii][1] = rdA(buf, (i0)+ii, 1); } } while (0)
#define G8_RDB(buf, j0) do { _Pragma("unroll") \
    for (int jj = 0; jj < 2; ++jj) { \
        Bf[(j0)+jj][0] = rdB(buf, (j0)+jj, 0); \
        Bf[(j0)+jj][1] = rdB(buf, (j0)+jj, 1); } } while (0)

template<int ACT, int LDA, int KK, typename TOUT>
__device__ __forceinline__ void gemm8_core(const ushort* __restrict__ A,
                                           const ushort* __restrict__ W,
                                           const float* __restrict__ bias,
                                           TOUT* __restrict__ C, int ldc,
                                           int m0, int n0) {
    __shared__ ushort ls[4][16384];   // [buf*2 + mat][256*64]; 128 KiB
    const int t = threadIdx.x;
    const int w = t >> 6, l = t & 63;
    const int q = l >> 4, r16 = l & 15;
    const int s7 = r16 & 7;
    const int wm = (w >> 2) * 128;    // wave row band (2 M-waves)
    const int wn = (w & 3) * 64;      // wave col band (4 N-waves)
    const int srow = t >> 3;          // 0..63
    const int lc = t & 7;

    const int gc = (lc ^ (srow & 7)) * 8;
    const ushort* baseA = A + (size_t)(m0 + srow) * LDA + gc;
    const ushort* baseW = W + (size_t)(n0 + srow) * KK + gc;
    const int aoff = (wm + r16) * 64;
    const int boff = (wn + r16) * 64;
    const int e0 = (q ^ s7) * 8;
    const int e1 = e0 ^ 32;

    floatx4 acc[8][4];
#pragma unroll
    for (int i = 0; i < 8; ++i)
#pragma unroll
        for (int j = 0; j < 4; ++j) acc[i][j] = (floatx4){0.f, 0.f, 0.f, 0.f};

    short8 Af[4][2], Bf[4][2];

    auto stage = [&](int buf, int mat, int half, int kt) {
        const ushort* bp = mat ? baseW : baseA;
#pragma unroll
        for (int L = 0; L < 2; ++L) {
            const ushort* gp = bp + (size_t)(half * 128 + L * 64) * (mat ? KK : LDA) + kt;
            ushort* lp = &ls[buf * 2 + mat][half * 8192 + L * 4096 + t * 8];
            G8_GLDS(gp, lp);
        }
    };
    auto rdA = [&](int buf, int i, int s) -> short8 {
        return *(const short8*)&ls[buf * 2][aoff + i * 1024 + (s ? e1 : e0)];
    };
    auto rdB = [&](int buf, int j, int s) -> short8 {
        return *(const short8*)&ls[buf * 2 + 1][boff + j * 1024 + (s ? e1 : e0)];
    };

    const int NT = KK >> 6;   // even

    // prologue: buf0 full (8) + buf1-B (4) + buf1-A-h0 (2); VM(6) -> buf0 done
    stage(0, 0, 0, 0);  stage(0, 0, 1, 0);  stage(0, 1, 0, 0);  stage(0, 1, 1, 0);
    stage(1, 1, 0, 64); stage(1, 1, 1, 64); stage(1, 0, 0, 64);
    G8_VM(6);
    G8_BAR();

    for (int tt = 0; tt < NT; tt += 2) {
        const bool pf = (tt + 2) < NT;
        const int kO  = (tt + 1) << 6;
        const int kE2 = (tt + 2) << 6;
        const int kO2 = (tt + 3) << 6;

        // ---- p1: q1(even); stage buf1-A-h1 @ kO ----
        G8_RDA(0, 0); G8_RDB(0, 0);
        stage(1, 0, 1, kO);
        G8_BAR(); G8_LGKM0();
        G8_QUAD(0, 0);
        G8_BAR();
        // ---- p2: q2(even); no stage ----
        G8_RDB(0, 2);
        G8_BAR(); G8_LGKM0();
        G8_QUAD(0, 2);
        G8_BAR();
        // ---- p3: q3(even); stage buf0-B-h0 @ kE2 ----
        G8_RDA(0, 4);
        if (pf) stage(0, 1, 0, kE2);
        G8_BAR(); G8_LGKM0();
        G8_QUAD(4, 0);
        G8_BAR();
        // ---- p4: q4(even); stage buf0-B-h1 + buf0-A-h0 @ kE2; fence buf1@kO ----
        if (pf) { stage(0, 1, 1, kE2); stage(0, 0, 0, kE2); }
        G8_BAR();
        G8_QUAD(4, 2);
        if (pf) G8_VM(6); else G8_VM(0);
        G8_BAR();
        // ---- p5: q1(odd); stage buf0-A-h1 @ kE2 ----
        G8_RDA(1, 0); G8_RDB(1, 0);
        if (pf) stage(0, 0, 1, kE2);
        G8_BAR(); G8_LGKM0();
        G8_QUAD(0, 0);
        G8_BAR();
        // ---- p6: q2(odd); no stage ----
        G8_RDB(1, 2);
        G8_BAR(); G8_LGKM0();
        G8_QUAD(0, 2);
        G8_BAR();
        // ---- p7: q3(odd); stage buf1-B-h0 @ kO2 ----
        G8_RDA(1, 4);
        if (pf) stage(1, 1, 0, kO2);
        G8_BAR(); G8_LGKM0();
        G8_QUAD(4, 0);
        G8_BAR();
        // ---- p8: q4(odd); stage buf1-B-h1 + buf1-A-h0 @ kO2; fence buf0@kE2 ----
        if (pf) { stage(1, 1, 1, kO2); stage(1, 0, 0, kO2); }
        G8_BAR();
        G8_QUAD(4, 2);
        if (pf) G8_VM(6);
        G8_BAR();
    }

    // epilogue: i outer / j inner (line-completing store order)
#pragma unroll
    for (int i = 0; i < 8; ++i) {
        const int row = m0 + wm + i * 16 + r16;
#pragma unroll
        for (int j = 0; j < 4; ++j) {
            const int col = n0 + wn + j * 16 + q * 4;
            const float4 bv = *(const float4*)(bias + col);
            float v0 = acc[i][j][0] + bv.x;
            float v1 = acc[i][j][1] + bv.y;
            float v2 = acc[i][j][2] + bv.z;
            float v3 = acc[i][j][3] + bv.w;
            if (ACT == 1) { v0 = gelu_f(v0); v1 = gelu_f(v1); v2 = gelu_f(v2); v3 = gelu_f(v3); }
            store4(&C[(size_t)row * ldc + col], v0, v1, v2, v3);
        }
    }
}

template<int ACT, int LDA, int KK, typename TOUT>
__global__ __launch_bounds__(512, 2) void gemm8_bt(const ushort* __restrict__ A,
                                                   const ushort* __restrict__ W,
                                                   const float* __restrict__ bias,
                                                   TOUT* __restrict__ C, int ldc,
                                                   int bh) {
    int2 xy = swz_xy(blockIdx.x, bh);
    gemm8_core<ACT, LDA, KK, TOUT>(A, W, bias, C, ldc, xy.y * 256, xy.x * 256);
}

// both embed GEMMs in one dispatch; A pre-converted to bf16 by cvt_all
__global__ __launch_bounds__(512, 2) void embed8_gemm(const ushort* __restrict__ A0,
                                                      const ushort* __restrict__ A1,
                                                      const ushort* __restrict__ W0,
                                                      const ushort* __restrict__ W1,
                                                      const float* __restrict__ b0,
                                                      const float* __restrict__ b1,
                                                      ushort* __restrict__ C) {
    const int z = blockIdx.z;
    int2 xy = swz_xy(blockIdx.x, 4);   // ny=32 -> bh=4
    gemm8_core<0, 512, 512, ushort>(z ? A1 : A0, z ? W1 : W0, z ? b1 : b0,
                                    C + z * 1024, 2048, xy.y * 256, xy.x * 256);
}

// ---------- LayerNorm in place over rows of combined (16384 x 1024 bf16) ----------
__global__ __launch_bounds__(256) void ln_kernel(ushort* __restrict__ comb,
                                                 const float* __restrict__ g1, const float* __restrict__ b1,
                                                 const float* __restrict__ g2, const float* __restrict__ b2) {
    int row = blockIdx.x;
    int s = row & 1;
    const float* g = s ? g2 : g1;
    const float* bb = s ? b2 : b1;
    ushort* p = comb + (size_t)row * 1024;
    int t = threadIdx.x;
    ushort4 u = *(const ushort4*)(p + t * 4);
    float x0 = bf2f(u.x), x1 = bf2f(u.y), x2 = bf2f(u.z), x3 = bf2f(u.w);
    float sum = x0 + x1 + x2 + x3;
    float ss = x0 * x0 + x1 * x1 + x2 * x2 + x3 * x3;
#pragma unroll
    for (int off = 32; off; off >>= 1) {
        sum += __shfl_xor(sum, off);
        ss  += __shfl_xor(ss, off);
    }
    __shared__ float sm[8];
    int wv = t >> 6, l = t & 63;
    if (l == 0) { sm[wv * 2] = sum; sm[wv * 2 + 1] = ss; }
    __syncthreads();
    sum = sm[0] + sm[2] + sm[4] + sm[6];
    ss  = sm[1] + sm[3] + sm[5] + sm[7];
    float mean = sum * (1.0f / 1024.0f);
    float var  = ss * (1.0f / 1024.0f) - mean * mean;
    float rstd = rsqrtf(var + 1e-5f);
    float4 gv = *(const float4*)(g + t * 4);
    float4 bv = *(const float4*)(bb + t * 4);
    ushort4 o;
    o.x = f2bf((x0 - mean) * rstd * gv.x + bv.x);
    o.y = f2bf((x1 - mean) * rstd * gv.y + bv.y);
    o.z = f2bf((x2 - mean) * rstd * gv.z + bv.z);
    o.w = f2bf((x3 - mean) * rstd * gv.w + bv.w);
    *(ushort4*)(p + t * 4) = o;
}

// ---------- attention (R9-best): one block per pair; LDS-staged; compact O ----------
// R10 A/B: direct-load variant was null-to-negative (kernel is BW-bound at
// full occupancy -> LDS round-trip is off the critical path; 16B/lane x3
// staging loads beat 8B/lane x6 direct loads on request count). Keep R9.
__global__ __launch_bounds__(256) void attn_kernel(const ushort* __restrict__ qkv,
                                                   ushort* __restrict__ O) {
    __shared__ ushort ls[6144];
    const int b = blockIdx.x;
    const int t = threadIdx.x;
    const ushort* src = qkv + (size_t)b * 6144;
#pragma unroll
    for (int p = 0; p < 3; ++p) {
        int idx = (p * 256 + t) * 8;
        *(ushort8v*)&ls[idx] = *(const ushort8v*)&src[idx];
    }
    __syncthreads();
    const int h = t >> 5, d32 = t & 31;
    const int o0 = h * 128 + d32 * 4;
    ushort4 uq0 = *(const ushort4*)&ls[o0];
    ushort4 uq1 = *(const ushort4*)&ls[3072 + o0];
    ushort4 uk0 = *(const ushort4*)&ls[1024 + o0];
    ushort4 uk1 = *(const ushort4*)&ls[4096 + o0];
    ushort4 uv0 = *(const ushort4*)&ls[2048 + o0];
    ushort4 uv1 = *(const ushort4*)&ls[5120 + o0];
    float q0[4] = {bf2f(uq0.x), bf2f(uq0.y), bf2f(uq0.z), bf2f(uq0.w)};
    float q1[4] = {bf2f(uq1.x), bf2f(uq1.y), bf2f(uq1.z), bf2f(uq1.w)};
    float k0[4] = {bf2f(uk0.x), bf2f(uk0.y), bf2f(uk0.z), bf2f(uk0.w)};
    float k1[4] = {bf2f(uk1.x), bf2f(uk1.y), bf2f(uk1.z), bf2f(uk1.w)};
    float v0[4] = {bf2f(uv0.x), bf2f(uv0.y), bf2f(uv0.z), bf2f(uv0.w)};
    float v1[4] = {bf2f(uv1.x), bf2f(uv1.y), bf2f(uv1.z), bf2f(uv1.w)};
    float p00 = 0.f, p01 = 0.f, p10 = 0.f, p11 = 0.f;
#pragma unroll
    for (int i = 0; i < 4; i++) {
        p00 += q0[i] * k0[i];
        p01 += q0[i] * k1[i];
        p10 += q1[i] * k0[i];
        p11 += q1[i] * k1[i];
    }
#pragma unroll
    for (int off = 16; off; off >>= 1) {
        p00 += __shfl_xor(p00, off);
        p01 += __shfl_xor(p01, off);
        p10 += __shfl_xor(p10, off);
        p11 += __shfl_xor(p11, off);
    }
    const float sc = 0.08838834764831845f;  // 1/sqrt(128)
    p00 *= sc; p01 *= sc; p10 *= sc; p11 *= sc;
    float m0 = fmaxf(p00, p01), m1 = fmaxf(p10, p11);
    float e00 = expf(p00 - m0), e01 = expf(p01 - m0);
    float e10 = expf(p10 - m1), e11 = expf(p11 - m1);
    float i0 = 1.0f / (e00 + e01), i1 = 1.0f / (e10 + e11);
    float a00 = e00 * i0, a01 = e01 * i0;
    float a10 = e10 * i1, a11 = e11 * i1;
    ushort* dst0 = O + (size_t)(b * 2) * 1024 + o0;
    ushort* dst1 = dst0 + 1024;
    store4(dst0, a00 * v0[0] + a01 * v1[0], a00 * v0[1] + a01 * v1[1],
                 a00 * v0[2] + a01 * v1[2], a00 * v0[3] + a01 * v1[3]);
    store4(dst1, a10 * v0[0] + a11 * v1[0], a10 * v0[1] + a11 * v1[1],
                 a10 * v0[2] + a11 * v1[2], a10 * v0[3] + a11 * v1[3]);
}

// ---------- gate2 (dot over 1024 x2) + softmax + fused combine ----------
__global__ __launch_bounds__(256) void gate2_kernel(const ushort* __restrict__ gate_h,
                                                    const float* __restrict__ w2, const float* __restrict__ b2,
                                                    const ushort* __restrict__ attn_out,
                                                    ushort* __restrict__ fused_pre,
                                                    float* __restrict__ gw_out) {
    int b = blockIdx.x;
    int t = threadIdx.x;
    const ushort* hp = gate_h + (size_t)b * 1024;
    ushort4 u = *(const ushort4*)(hp + t * 4);
    float4 w0 = *(const float4*)(w2 + t * 4);
    float4 w1 = *(const float4*)(w2 + 1024 + t * 4);
    float h0 = bf2f(u.x), h1 = bf2f(u.y), h2 = bf2f(u.z), h3 = bf2f(u.w);
    float p0 = h0 * w0.x + h1 * w0.y + h2 * w0.z + h3 * w0.w;
    float p1 = h0 * w1.x + h1 * w1.y + h2 * w1.z + h3 * w1.w;
#pragma unroll
    for (int off = 32; off; off >>= 1) {
        p0 += __shfl_xor(p0, off);
        p1 += __shfl_xor(p1, off);
    }
    __shared__ float sm[8];
    __shared__ float sgw[2];
    int wv = t >> 6, l = t & 63;
    if (l == 0) { sm[wv * 2] = p0; sm[wv * 2 + 1] = p1; }
    __syncthreads();
    if (t == 0) {
        float d0 = sm[0] + sm[2] + sm[4] + sm[6] + b2[0];
        float d1 = sm[1] + sm[3] + sm[5] + sm[7] + b2[1];
        float mx = fmaxf(d0, d1);
        float e0 = expf(d0 - mx), e1 = expf(d1 - mx);
        float inv = 1.0f / (e0 + e1);
        sgw[0] = e0 * inv; sgw[1] = e1 * inv;
        gw_out[b * 2] = e0 * inv;
        gw_out[b * 2 + 1] = e1 * inv;
    }
    __syncthreads();
    float g0 = sgw[0], g1 = sgw[1];
    const ushort* ca = attn_out + (size_t)b * 2048;
    ushort* fp = fused_pre + (size_t)b * 1024;
    ushort4 uc = *(const ushort4*)(ca + t * 4);
    ushort4 ug = *(const ushort4*)(ca + 1024 + t * 4);
    ushort4 o;
    o.x = f2bf(g0 * bf2f(uc.x) + g1 * bf2f(ug.x));
    o.y = f2bf(g0 * bf2f(uc.y) + g1 * bf2f(ug.y));
    o.z = f2bf(g0 * bf2f(uc.z) + g1 * bf2f(ug.z));
    o.w = f2bf(g0 * bf2f(uc.w) + g1 * bf2f(ug.w));
    *(ushort4*)(fp + t * 4) = o;
}

// ---------- workspace layout (bytes) ----------
// [0, 16M): bf16 embeds (e_cnn 8 MB, e_gnn 8 MB)
// OFF_COMB region is time-multiplexed: comb -> O -> gate_h / fused_pre
#define OFF_E_CNN  0u
#define OFF_E_GNN  8388608u
#define OFF_W_CNN  16777216u
#define OFF_W_GNN  17825792u
#define OFF_W_QKV  18874368u
#define OFF_W_AO   25165824u
#define OFF_W_G1   27262976u
#define OFF_W_PJ   31457280u
#define OFF_COMB   33554432u
#define OFF_QKV    67108864u   /* 16384x3072 bf16 */
#define OFF_AO     167772160u  /* 16384x1024 bf16 == gate_in (8192 x 2048) */

extern "C" void kernel_launch(void* const* d_in, const int* in_sizes, int n_in,
                              void* d_out, int out_size, void* d_ws, size_t ws_size,
                              hipStream_t stream) {
    const float* cnn_embed  = (const float*)d_in[0];
    const float* gnn_embed  = (const float*)d_in[1];
    const float* cnn_w      = (const float*)d_in[2];
    const float* cnn_b      = (const float*)d_in[3];
    const float* gnn_w      = (const float*)d_in[4];
    const float* gnn_b      = (const float*)d_in[5];
    const float* ln1_g      = (const float*)d_in[6];
    const float* ln1_b      = (const float*)d_in[7];
    const float* ln2_g      = (const float*)d_in[8];
    const float* ln2_b      = (const float*)d_in[9];
    const float* attn_in_w  = (const float*)d_in[10];
    const float* attn_in_b  = (const float*)d_in[11];
    const float* attn_out_w = (const float*)d_in[12];
    const float* attn_out_b = (const float*)d_in[13];
    const float* gate_w1    = (const float*)d_in[14];
    const float* gate_b1    = (const float*)d_in[15];
    const float* gate_w2    = (const float*)d_in[16];
    const float* gate_b2    = (const float*)d_in[17];
    const float* proj_w     = (const float*)d_in[18];
    const float* proj_b     = (const float*)d_in[19];

    char* ws = (char*)d_ws;
    ushort* e_cnn  = (ushort*)(ws + OFF_E_CNN);
    ushort* e_gnn  = (ushort*)(ws + OFF_E_GNN);
    ushort* w_cnn  = (ushort*)(ws + OFF_W_CNN);
    ushort* w_gnn  = (ushort*)(ws + OFF_W_GNN);
    ushort* w_qkv  = (ushort*)(ws + OFF_W_QKV);
    ushort* w_ao   = (ushort*)(ws + OFF_W_AO);
    ushort* w_g1   = (ushort*)(ws + OFF_W_G1);
    ushort* w_pj   = (ushort*)(ws + OFF_W_PJ);
    ushort* comb   = (ushort*)(ws + OFF_COMB);
    ushort* qkv    = (ushort*)(ws + OFF_QKV);
    ushort* ao     = (ushort*)(ws + OFF_AO);
    ushort* Obuf      = (ushort*)(ws + OFF_COMB);              // alias: comb dead after qkv GEMM
    ushort* gate_h    = (ushort*)(ws + OFF_COMB);              // alias: O dead after attn_out GEMM
    ushort* fused_pre = (ushort*)(ws + OFF_COMB + 16777216u);

    float* out_f  = (float*)d_out;
    float* gw_out = out_f + 8192 * 1024;

    // ---- fp32 -> bf16 converts (weights + both embeds) in one dispatch ----
    CvtDesc cd;
    cd.in[0] = cnn_w;      cd.out[0] = w_cnn; cd.nblk[0] = 512;
    cd.in[1] = gnn_w;      cd.out[1] = w_gnn; cd.nblk[1] = 512;
    cd.in[2] = attn_in_w;  cd.out[2] = w_qkv; cd.nblk[2] = 3072;
    cd.in[3] = attn_out_w; cd.out[3] = w_ao;  cd.nblk[3] = 1024;
    cd.in[4] = gate_w1;    cd.out[4] = w_g1;  cd.nblk[4] = 2048;
    cd.in[5] = proj_w;     cd.out[5] = w_pj;  cd.nblk[5] = 1024;
    cd.in[6] = cnn_embed;  cd.out[6] = e_cnn; cd.nblk[6] = 4096;
    cd.in[7] = gnn_embed;  cd.out[7] = e_gnn; cd.nblk[7] = 4096;
    cvt_all_kernel<<<16384, 256, 0, stream>>>(cd);

    dim3 blk256(256);
    dim3 blk512(512);

    // ---- both embed GEMMs (8-phase DEEP depinned; nx=4, ny=32, bh=4) ----
    embed8_gemm<<<dim3(128, 1, 2), blk512, 0, stream>>>(e_cnn, e_gnn, w_cnn, w_gnn,
                                                        cnn_b, gnn_b, comb);

    // ---- LayerNorm in place ----
    ln_kernel<<<16384, blk256, 0, stream>>>(comb, ln1_g, ln1_b, ln2_g, ln2_b);

    // ---- qkv GEMM: v1 128^2 (per-dispatch winner; nx=24, ny=128, bh=16) ----
    gemm_bt<0, ushort><<<24 * 128, blk256, 0, stream>>>(comb, 1024, w_qkv, attn_in_b,
                                                        qkv, 3072, 1024, 16);

    // ---- attention -> compact O (R9 LDS version) ----
    attn_kernel<<<8192, blk256, 0, stream>>>(qkv, Obuf);

    // ---- attn_out GEMM (8-phase DEEP depinned 256^2; nx=4, ny=64, bh=8) ----
    gemm8_bt<0, 1024, 1024, ushort><<<4 * 64, blk512, 0, stream>>>(Obuf, w_ao, attn_out_b,
                                                                   ao, 1024, 8);

    // ---- gate1 GEMM (gelu) (v1 128^2: nx=8, ny=64, bh=8 -> 512 blocks) ----
    gemm_bt<1, ushort><<<8 * 64, blk256, 0, stream>>>(ao, 2048, w_g1, gate_b1, gate_h, 1024, 2048, 8);

    // ---- gate2 + softmax + fused combine ----
    gate2_kernel<<<8192, blk256, 0, stream>>>(gate_h, gate_w2, gate_b2, ao, fused_pre, gw_out);

    // ---- proj GEMM (gelu) -> out (v1 128^2: nx=8, ny=64, bh=8) ----
    gemm_bt<1, float><<<8 * 64, blk256, 0, stream>>>(fused_pre, 1024, w_pj, proj_b, out_f, 1024, 1024, 8);
}